// Round 5
// baseline (916.612 us; speedup 1.0000x reference)
//
#include <hip/hip_runtime.h>
#include <hip/hip_bf16.h>
#include <cstdint>
#include <cstddef>

#define Sd 1024
#define Dd 512
#define Hd 8
#define Fd 2048
#define Bd 8
#define EPSf 1e-3f

typedef __bf16 bf16x8 __attribute__((ext_vector_type(8)));
typedef float f32x4 __attribute__((ext_vector_type(4)));
typedef __attribute__((address_space(3))) unsigned int lds_u32;
typedef __attribute__((address_space(1))) const unsigned int gl_u32;

#define BM 128
#define BN 128
#define BK 32

enum { EPI_BF16 = 0, EPI_F32 = 1, EPI_BNPRELU = 2, EPI_SCORES = 3 };

__device__ __forceinline__ void gl_lds16(const void* g, void* l) {
  __builtin_amdgcn_global_load_lds((gl_u32*)g, (lds_u32*)l, 16, 0, 0);
}

// ======================================================================
// 256x256 8-phase GEMM (T1+T2+T3+T4+T5): C[M,N] = epi(A @ Bt^T + bias)
// A [M,K] bf16 (lda=K), Bt [N,K] bf16 (ldb=K). Requires M%256==0, N%256==0,
// K%64==0, K>=128, grid (N/256, M/256) with (gx*gy)%8==0. 512 threads.
// LDS 128KiB: dbuf d in {0,1}: A0|A1|B0|B1 half-tile regions of 16KiB
// (128 rows x 64 k bf16). Swizzle: 16B-chunk index ^= (row&7), applied
// pre-swizzled on the global source (linear global_load_lds dest) and on
// the ds_read address (rule #21 both-sides involution).
// Region schedule per K-tile u (cur=u&1, nxt=cur^1), verified liveness:
//   p1: read s0 mi0-3 + B s0 ; stage nxt.B1 <- K-tile u+1 (last read u-1.p3)
//   p2: read s0 mi4-7        ; stage nxt.A0 <- u+1        (last read u-1.p4)
//   p3: read s1 mi0-3 + B s1 ; stage nxt.A1 <- u+1        (last read u-1.p4)
//   p4: read s1 mi4-7        ; stage cur.B0 <- u+2        (last read u.p3)
// End-of-tile vmcnt(2): all stages except the newest half-tile (2 loads)
// retired in-order -> next tile's 4 half-tiles have landed. Tail: vmcnt(0).
// ======================================================================

#define BG_SYNC1()                                    \
  __builtin_amdgcn_s_barrier();                       \
  asm volatile("s_waitcnt lgkmcnt(0)" ::: "memory");  \
  __builtin_amdgcn_sched_barrier(0)

#define BG_MFMA(MH)                                                          \
  __builtin_amdgcn_s_setprio(1);                                             \
  {                                                                          \
    _Pragma("unroll") for (int i_ = 0; i_ < 4; ++i_) {                       \
      _Pragma("unroll") for (int n_ = 0; n_ < 4; ++n_)                       \
          acc[(MH)*4 + i_][n_] = __builtin_amdgcn_mfma_f32_16x16x32_bf16(    \
              a[i_], b[n_], acc[(MH)*4 + i_][n_], 0, 0, 0);                  \
    }                                                                        \
  }                                                                          \
  __builtin_amdgcn_s_setprio(0)

template <int EPI>
__global__ __launch_bounds__(512, 2) void big_gemm(
    const __hip_bfloat16* __restrict__ A_,
    const __hip_bfloat16* __restrict__ B_,
    const float* __restrict__ bias_,
    void* __restrict__ C_, int ldc, int K,
    const float* __restrict__ bn_g, const float* __restrict__ bn_b,
    const float* __restrict__ bn_m, const float* __restrict__ bn_v,
    const float* __restrict__ pa) {
  __shared__ __align__(16) char lds[131072];
  const int tid = threadIdx.x;
  // bijective XCD swizzle (nwg % 8 == 0 for all users)
  const int gx = gridDim.x;
  const int nwg = gx * gridDim.y;
  const int orig = blockIdx.y * gx + blockIdx.x;
  const int wgid = (orig & 7) * (nwg >> 3) + (orig >> 3);
  const int bx = wgid % gx;
  const int by = wgid / gx;
  const int m0 = by * 256, n0 = bx * 256;

  const int lane = tid & 63;
  const int wid = tid >> 6;
  const int wm = wid >> 2;   // 2 M-waves
  const int wn = wid & 3;    // 4 N-waves
  const int fr = lane & 15;
  const int kg = lane >> 4;

  // staging: lds slot seq = tid (+512); row r0 = seq>>3, swz chunk -> global
  // chunk c0 = (seq&7) ^ (r0&7); second load is row +64 (same low-3 row bits).
  const int r0 = tid >> 3;
  const int c0 = (tid & 7) ^ (r0 & 7);
  const size_t ldb = (size_t)K * 2;
  const char* Ab = (const char*)A_ + (size_t)(m0 + r0) * ldb + c0 * 16;
  const char* Bb = (const char*)B_ + (size_t)(n0 + r0) * ldb + c0 * 16;

  auto STAGE = [&](int d, int part, int half, const char* base, int u) {
    char* L = lds + (d << 16) + (part << 15) + (half << 14) + tid * 16;
    const char* src = base + (size_t)(half * 128) * ldb + (size_t)u * 128;
    gl_lds16(src, L);
    gl_lds16(src + 64 * ldb, L + 8192);
  };
  auto LDA = [&](int d, int s, int mh, bf16x8* v) {
    const char* base = lds + (d << 16) + (wm << 14);
#pragma unroll
    for (int i = 0; i < 4; ++i) {
      const int r = (mh * 4 + i) * 16 + fr;
      v[i] = *(const bf16x8*)(base + r * 128 + (((s * 4 + kg) ^ (r & 7)) << 4));
    }
  };
  auto LDB = [&](int d, int s, bf16x8* v) {
    const char* base = lds + (d << 16) + 32768 + ((wn >> 1) << 14);
#pragma unroll
    for (int i = 0; i < 4; ++i) {
      const int r = (wn & 1) * 64 + i * 16 + fr;
      v[i] = *(const bf16x8*)(base + r * 128 + (((s * 4 + kg) ^ (r & 7)) << 4));
    }
  };

  f32x4 acc[8][4] = {};
  const int NT = K >> 6;

  // prologue: K-tile 0 fully -> d0; B0 of K-tile 1 -> d1
  STAGE(0, 0, 0, Ab, 0);
  STAGE(0, 0, 1, Ab, 0);
  STAGE(0, 1, 0, Bb, 0);
  STAGE(0, 1, 1, Bb, 0);
  if (NT > 1) STAGE(1, 1, 0, Bb, 1);
  asm volatile("s_waitcnt vmcnt(2)" ::: "memory");
  __builtin_amdgcn_s_barrier();

  for (int u = 0; u < NT; ++u) {
    const int cur = u & 1, nxt = cur ^ 1;
    bf16x8 a[4], b[4];
    // ---- phase 1 ----
    LDA(cur, 0, 0, a);
    LDB(cur, 0, b);
    if (u + 1 < NT) STAGE(nxt, 1, 1, Bb, u + 1);
    BG_SYNC1();
    BG_MFMA(0);
    __builtin_amdgcn_s_barrier();
    // ---- phase 2 ----
    LDA(cur, 0, 1, a);
    if (u + 1 < NT) STAGE(nxt, 0, 0, Ab, u + 1);
    BG_SYNC1();
    BG_MFMA(1);
    __builtin_amdgcn_s_barrier();
    // ---- phase 3 ----
    LDA(cur, 1, 0, a);
    LDB(cur, 1, b);
    if (u + 1 < NT) STAGE(nxt, 0, 1, Ab, u + 1);
    BG_SYNC1();
    BG_MFMA(0);
    __builtin_amdgcn_s_barrier();
    // ---- phase 4 ----
    LDA(cur, 1, 1, a);
    if (u + 2 < NT) STAGE(cur, 1, 0, Bb, u + 2);
    BG_SYNC1();
    BG_MFMA(1);
    if (u < NT - 2) {
      asm volatile("s_waitcnt vmcnt(2)" ::: "memory");
    } else {
      asm volatile("s_waitcnt vmcnt(0)" ::: "memory");
    }
    __builtin_amdgcn_s_barrier();
  }

  // epilogue: C/D layout col=lane&15, row=(lane>>4)*4+j [m89-verified]
  char* C = (char*)C_;
#pragma unroll
  for (int ni = 0; ni < 4; ++ni) {
    const int col = n0 + wn * 64 + ni * 16 + fr;
    float bcol = 0.f, scale = 0.f, shift = 0.f;
    if (EPI != EPI_BF16) bcol = bias_[col];
    if (EPI == EPI_BNPRELU) {
      scale = bn_g[col] * rsqrtf(bn_v[col] + EPSf);
      shift = bn_b[col] - bn_m[col] * scale;
    }
#pragma unroll
    for (int mi = 0; mi < 8; ++mi) {
      const int rb = m0 + wm * 128 + mi * 16 + kg * 4;
#pragma unroll
      for (int j = 0; j < 4; ++j) {
        const int row = rb + j;
        float v = acc[mi][ni][j] + bcol;
        if (EPI == EPI_F32) {
          ((float*)C)[(size_t)row * ldc + col] = v;
        } else if (EPI == EPI_BF16) {
          ((__hip_bfloat16*)C)[(size_t)row * ldc + col] = __float2bfloat16(v);
        } else {
          v = v * scale + shift;
          const float aa = pa[(size_t)(row & (Sd - 1)) * Fd + col];
          v = v > 0.f ? v : aa * v;
          ((__hip_bfloat16*)C)[(size_t)row * ldc + col] = __float2bfloat16(v);
        }
      }
    }
  }
}

// ---- m97-structure BT-GEMM (kept for scores/PV/mha/FF3/folding) ----
template <int EPI>
__global__ __launch_bounds__(256, 2) void bt_gemm(
    const __hip_bfloat16* __restrict__ A_, int lda, size_t sA1, size_t sA2,
    const __hip_bfloat16* __restrict__ B_, int ldb, size_t sB1, size_t sB2,
    const float* __restrict__ bias_, size_t sBi1, size_t sBi2,
    void* __restrict__ C_, int ldc, size_t sC1, size_t sC2,
    int K, float alpha, int zshift,
    const float* __restrict__ bn_g, const float* __restrict__ bn_b,
    const float* __restrict__ bn_m, const float* __restrict__ bn_v,
    const float* __restrict__ pa) {
  __shared__ __hip_bfloat16 As[BM * BK];
  __shared__ __hip_bfloat16 Bs[BN * BK];

  const int tid = threadIdx.x;
  const int z = blockIdx.z;
  const int z1 = z >> zshift;
  const int z2 = z & ((1 << zshift) - 1);
  const int m0 = blockIdx.y * BM;
  const int n0 = blockIdx.x * BN;

  const __hip_bfloat16* A = A_ + (size_t)z1 * sA1 + (size_t)z2 * sA2;
  const __hip_bfloat16* Bt = B_ + (size_t)z1 * sB1 + (size_t)z2 * sB2;
  const float* bi = bias_ ? bias_ + (size_t)z1 * sBi1 + (size_t)z2 * sBi2 : nullptr;

  const int lane = tid & 63;
  const int wv = tid >> 6;
  const int wm = (wv >> 1) * 64;
  const int wn = (wv & 1) * 64;
  const int fr = lane & 15;
  const int kg = lane >> 4;

  const int srow = tid >> 2, sch = tid & 3;
  const size_t ldab = (size_t)lda * 2, ldbb = (size_t)ldb * 2;
  const char* Ap = (const char*)A + (size_t)(m0 + srow) * ldab + sch * 16;
  const char* Ap2 = Ap + 64 * ldab;
  const char* Bp = (const char*)Bt + (size_t)(n0 + srow) * ldbb + sch * 16;
  const char* Bp2 = Bp + 64 * ldbb;
  char* lA = (char*)As + tid * 16;
  char* lB = (char*)Bs + tid * 16;

  f32x4 acc[4][4] = {};

  for (int kt = 0; kt < K; kt += BK) {
    const size_t kb = (size_t)kt * 2;
    gl_lds16(Ap + kb, lA);
    gl_lds16(Ap2 + kb, lA + 4096);
    gl_lds16(Bp + kb, lB);
    gl_lds16(Bp2 + kb, lB + 4096);
    __syncthreads();

    bf16x8 afr[4], bfr[4];
#pragma unroll
    for (int mi = 0; mi < 4; ++mi)
      afr[mi] = *reinterpret_cast<const bf16x8*>(As + (wm + mi * 16 + fr) * BK + kg * 8);
#pragma unroll
    for (int ni = 0; ni < 4; ++ni)
      bfr[ni] = *reinterpret_cast<const bf16x8*>(Bs + (wn + ni * 16 + fr) * BK + kg * 8);
#pragma unroll
    for (int mi = 0; mi < 4; ++mi)
#pragma unroll
      for (int ni = 0; ni < 4; ++ni)
        acc[mi][ni] = __builtin_amdgcn_mfma_f32_16x16x32_bf16(afr[mi], bfr[ni], acc[mi][ni], 0, 0, 0);
    __syncthreads();
  }

  char* C = (char*)C_ + ((size_t)z1 * sC1 + (size_t)z2 * sC2) * ((EPI == EPI_F32) ? 4 : 2);
  const float cs = (EPI == EPI_SCORES) ? bn_m[z2] : 0.f;
#pragma unroll
  for (int ni = 0; ni < 4; ++ni) {
    const int col = n0 + wn + ni * 16 + fr;
    float bcol = 0.f, scale = 0.f, shift = 0.f;
    if (bi) bcol = bi[col];
    if (EPI == EPI_BNPRELU) {
      scale = bn_g[col] * rsqrtf(bn_v[col] + EPSf);
      shift = bn_b[col] - bn_m[col] * scale;
    }
    const float wcol = (EPI == EPI_SCORES) ? bn_b[z2 * 8192 + col] : 0.f;
#pragma unroll
    for (int mi = 0; mi < 4; ++mi) {
      const int rb = m0 + wm + mi * 16 + kg * 4;
#pragma unroll
      for (int j = 0; j < 4; ++j) {
        const int row = rb + j;
        float v;
        if (EPI == EPI_SCORES) {
          v = (acc[mi][ni][j] + bn_g[z2 * 8192 + row] + wcol + cs) * alpha;
          ((__hip_bfloat16*)C)[(size_t)row * ldc + col] = __float2bfloat16(v);
        } else {
          v = acc[mi][ni][j] * alpha + bcol;
          if (EPI == EPI_F32) {
            ((float*)C)[(size_t)row * ldc + col] = v;
          } else if (EPI == EPI_BF16) {
            ((__hip_bfloat16*)C)[(size_t)row * ldc + col] = __float2bfloat16(v);
          } else {
            v = v * scale + shift;
            const float a = pa[(size_t)(row & (Sd - 1)) * Fd + col];
            v = v > 0.f ? v : a * v;
            ((__hip_bfloat16*)C)[(size_t)row * ldc + col] = __float2bfloat16(v);
          }
        }
      }
    }
  }
}

// ---- transpose + convert: src [K][N] f32 -> dst [N][Kfull] bf16 ----
__global__ __launch_bounds__(256) void tconv(const float* __restrict__ src,
                                             __hip_bfloat16* __restrict__ dst,
                                             int N, int Kfull, size_t sIn, size_t sOut) {
  __shared__ __hip_bfloat16 t[64][65];
  const float* s = src + (size_t)blockIdx.z * sIn;
  __hip_bfloat16* d = dst + (size_t)blockIdx.z * sOut;
  const int k0 = blockIdx.y * 64, n0 = blockIdx.x * 64;
  const int tid = threadIdx.x;
#pragma unroll
  for (int i = 0; i < 4; ++i) {
    int slot = tid + i * 256;
    int r = slot >> 4, c = (slot & 15) * 4;
    const float4 v = *reinterpret_cast<const float4*>(s + (size_t)(k0 + r) * N + n0 + c);
    t[c + 0][r] = __float2bfloat16(v.x);
    t[c + 1][r] = __float2bfloat16(v.y);
    t[c + 2][r] = __float2bfloat16(v.z);
    t[c + 3][r] = __float2bfloat16(v.w);
  }
  __syncthreads();
#pragma unroll
  for (int i = 0; i < 2; ++i) {
    int slot = tid + i * 256;
    int n = slot >> 3, kc = (slot & 7) * 8;
    __hip_bfloat16 tmp[8];
#pragma unroll
    for (int j = 0; j < 8; ++j) tmp[j] = t[n][kc + j];
    *reinterpret_cast<float4*>(d + (size_t)(n0 + n) * Kfull + k0 + kc) =
        *reinterpret_cast<const float4*>(tmp);
  }
}

// ---- f32 -> bf16 elementwise; grid (nblk, ntensors), 8 elems/thread ----
__global__ __launch_bounds__(256) void conv3(const float* __restrict__ s0, const float* __restrict__ s1,
                                             const float* __restrict__ s2,
                                             __hip_bfloat16* __restrict__ d0, __hip_bfloat16* __restrict__ d1,
                                             __hip_bfloat16* __restrict__ d2) {
  const float* s = blockIdx.y == 0 ? s0 : (blockIdx.y == 1 ? s1 : s2);
  __hip_bfloat16* d = blockIdx.y == 0 ? d0 : (blockIdx.y == 1 ? d1 : d2);
  const size_t i = (size_t)blockIdx.x * 256 + threadIdx.x;
  const float4 a = reinterpret_cast<const float4*>(s)[2 * i];
  const float4 b = reinterpret_cast<const float4*>(s)[2 * i + 1];
  __hip_bfloat16 tmp[8] = {
      __float2bfloat16(a.x), __float2bfloat16(a.y), __float2bfloat16(a.z), __float2bfloat16(a.w),
      __float2bfloat16(b.x), __float2bfloat16(b.y), __float2bfloat16(b.z), __float2bfloat16(b.w)};
  *reinterpret_cast<float4*>(d + 8 * i) = *reinterpret_cast<const float4*>(tmp);
}

// ---- reductions ----
__device__ inline float wave_max(float v) {
#pragma unroll
  for (int o = 32; o > 0; o >>= 1) v = fmaxf(v, __shfl_xor(v, o));
  return v;
}
__device__ inline float wave_sum(float v) {
#pragma unroll
  for (int o = 32; o > 0; o >>= 1) v += __shfl_xor(v, o);
  return v;
}

__device__ inline float b2f(unsigned short u) {
  unsigned x = ((unsigned)u) << 16; float f; __builtin_memcpy(&f, &x, 4); return f;
}
__device__ inline unsigned short f2b(float f) {
  __hip_bfloat16 h = __float2bfloat16(f); unsigned short u; __builtin_memcpy(&u, &h, 2); return u;
}

// t1[hd] = sum_e WQ[h][d][e]*bK[h][e] (y=0); t2[hd] = sum_e WK[h][d][e]*bQ[h][e] (y=1)
__global__ __launch_bounds__(256) void tvec(const float* __restrict__ WQ, const float* __restrict__ bK,
                                            const float* __restrict__ WK, const float* __restrict__ bQ,
                                            float* __restrict__ t1, float* __restrict__ t2) {
  const float* W = blockIdx.y == 0 ? WQ : WK;
  const float* bb = blockIdx.y == 0 ? bK : bQ;
  float* out = blockIdx.y == 0 ? t1 : t2;
  const int wv = threadIdx.x >> 6, lane = threadIdx.x & 63;
  const int hd = blockIdx.x * 4 + wv;
  const int h = hd >> 9;
  float acc = 0.f;
#pragma unroll
  for (int j = 0; j < 8; ++j) {
    const int e = lane + 64 * j;
    acc += W[(size_t)hd * 512 + e] * bb[h * 512 + e];
  }
  acc = wave_sum(acc);
  if (lane == 0) out[hd] = acc;
}

// u[h][row] = Q[row]·t1[h], w[h][row] = K[row]·t2[h]. grid (8192), 256 thr.
__global__ __launch_bounds__(256) void uw_kernel(const float* __restrict__ Q, const float* __restrict__ K,
                                                 const float* __restrict__ t1, const float* __restrict__ t2,
                                                 float* __restrict__ u, float* __restrict__ w) {
  const int tid = threadIdx.x;
  const size_t row = blockIdx.x;
  const float2 q = reinterpret_cast<const float2*>(Q + row * 512)[tid];
  const float2 k = reinterpret_cast<const float2*>(K + row * 512)[tid];
  const int c = tid * 2;
  __shared__ float redu[8][4], redw[8][4];
  const int wv = tid >> 6;
#pragma unroll
  for (int h = 0; h < 8; ++h) {
    float ua = q.x * t1[h * 512 + c] + q.y * t1[h * 512 + c + 1];
    float wa = k.x * t2[h * 512 + c] + k.y * t2[h * 512 + c + 1];
    ua = wave_sum(ua);
    wa = wave_sum(wa);
    if ((tid & 63) == 0) { redu[h][wv] = ua; redw[h][wv] = wa; }
  }
  __syncthreads();
  if (tid < 8)
    u[tid * 8192 + row] = redu[tid][0] + redu[tid][1] + redu[tid][2] + redu[tid][3];
  else if (tid < 16)
    w[(tid - 8) * 8192 + row] = redw[tid - 8][0] + redw[tid - 8][1] + redw[tid - 8][2] + redw[tid - 8][3];
}

// c[h] = bQ[h]·bK[h]. grid (8), 256 thr.
__global__ __launch_bounds__(256) void cvec(const float* __restrict__ bQ, const float* __restrict__ bK,
                                            float* __restrict__ c) {
  const int h = blockIdx.x, tid = threadIdx.x;
  const float2 a = reinterpret_cast<const float2*>(bQ + h * 512)[tid];
  const float2 b = reinterpret_cast<const float2*>(bK + h * 512)[tid];
  float acc = wave_sum(a.x * b.x + a.y * b.y);
  __shared__ float red[4];
  if ((tid & 63) == 0) red[tid >> 6] = acc;
  __syncthreads();
  if (tid == 0) c[h] = red[0] + red[1] + red[2] + red[3];
}

// bvo[e] = bo[e] + sum_hd wot[e][hd]*bV[hd]. grid (128), 256 thr.
__global__ __launch_bounds__(256) void bvo_kernel(const __hip_bfloat16* __restrict__ wot,
                                                  const float* __restrict__ bV,
                                                  const float* __restrict__ bo,
                                                  float* __restrict__ bvo) {
  const int wv = threadIdx.x >> 6, lane = threadIdx.x & 63;
  const int e = blockIdx.x * 4 + wv;
  float acc = 0.f;
#pragma unroll
  for (int j = 0; j < 64; ++j) {
    const int hd = lane + 64 * j;
    acc += b2f(*(const unsigned short*)&wot[(size_t)e * 4096 + hd]) * bV[hd];
  }
  acc = wave_sum(acc);
  if (lane == 0) bvo[e] = bo[e] + acc;
}

// softmax over rows of sc[h][1024][1024] bf16, in place. grid (1024, 8), 256 thr.
__global__ __launch_bounds__(256) void softmax_bf16(__hip_bfloat16* __restrict__ sc) {
  const int tid = threadIdx.x;
  __hip_bfloat16* rowp = sc + ((size_t)blockIdx.y << 20) + ((size_t)blockIdx.x << 10);
  const ushort4 r = reinterpret_cast<const ushort4*>(rowp)[tid];
  const float v0 = b2f(r.x), v1 = b2f(r.y), v2 = b2f(r.z), v3 = b2f(r.w);
  __shared__ float red[8];
  float mx = fmaxf(fmaxf(v0, v1), fmaxf(v2, v3));
  mx = wave_max(mx);
  if ((tid & 63) == 0) red[tid >> 6] = mx;
  __syncthreads();
  mx = fmaxf(fmaxf(red[0], red[1]), fmaxf(red[2], red[3]));
  const float e0 = __expf(v0 - mx), e1 = __expf(v1 - mx);
  const float e2 = __expf(v2 - mx), e3 = __expf(v3 - mx);
  float s = wave_sum(e0 + e1 + e2 + e3);
  if ((tid & 63) == 0) red[4 + (tid >> 6)] = s;
  __syncthreads();
  const float inv = 1.f / (red[4] + red[5] + red[6] + red[7]);
  ushort4 o;
  o.x = f2b(e0 * inv); o.y = f2b(e1 * inv); o.z = f2b(e2 * inv); o.w = f2b(e3 * inv);
  reinterpret_cast<ushort4*>(rowp)[tid] = o;
}

// out = LN(Xa + Xb)*gamma + beta (rows of 512); optional bf16 copy. grid(8192), 256 thr.
__global__ __launch_bounds__(256) void add_ln(const float* __restrict__ Xa, const float* __restrict__ Xb,
                                              const float* __restrict__ gamma, const float* __restrict__ beta,
                                              float* __restrict__ out, __hip_bfloat16* __restrict__ outb) {
  const int tid = threadIdx.x;
  const size_t base = (size_t)blockIdx.x * Dd;
  const float2 a = reinterpret_cast<const float2*>(Xa + base)[tid];
  const float2 b = reinterpret_cast<const float2*>(Xb + base)[tid];
  const float r0 = a.x + b.x, r1 = a.y + b.y;
  float s = wave_sum(r0 + r1);
  float q = wave_sum(r0 * r0 + r1 * r1);
  __shared__ float rs[4], rq[4];
  if ((tid & 63) == 0) { rs[tid >> 6] = s; rq[tid >> 6] = q; }
  __syncthreads();
  const float mean = (rs[0] + rs[1] + rs[2] + rs[3]) * (1.f / Dd);
  const float msq = (rq[0] + rq[1] + rq[2] + rq[3]) * (1.f / Dd);
  const float inv = rsqrtf(msq - mean * mean + EPSf);
  const int c = tid * 2;
  const float y0 = (r0 - mean) * inv * gamma[c] + beta[c];
  const float y1 = (r1 - mean) * inv * gamma[c + 1] + beta[c + 1];
  out[base + c] = y0;
  out[base + c + 1] = y1;
  if (outb) {
    outb[base + c] = __float2bfloat16(y0);
    outb[base + c + 1] = __float2bfloat16(y1);
  }
}

extern "C" void kernel_launch(void* const* d_in, const int* in_sizes, int n_in,
                              void* d_out, int out_size, void* d_ws, size_t ws_size,
                              hipStream_t stream) {
  const float* Q = (const float*)d_in[0];
  const float* K = (const float*)d_in[1];
  const float* V = (const float*)d_in[2];
  const float* WQ = (const float*)d_in[3];
  const float* bQ = (const float*)d_in[4];
  const float* WK = (const float*)d_in[5];
  const float* bK = (const float*)d_in[6];
  const float* WV = (const float*)d_in[7];
  const float* bV = (const float*)d_in[8];
  const float* Wo = (const float*)d_in[9];
  const float* bo = (const float*)d_in[10];
  const float* W0 = (const float*)d_in[11];
  const float* b0 = (const float*)d_in[12];
  const float* g0 = (const float*)d_in[13];
  const float* be0 = (const float*)d_in[14];
  const float* m0 = (const float*)d_in[15];
  const float* v0 = (const float*)d_in[16];
  const float* a0 = (const float*)d_in[17];
  const float* W1 = (const float*)d_in[18];
  const float* b1 = (const float*)d_in[19];
  const float* g1 = (const float*)d_in[20];
  const float* be1 = (const float*)d_in[21];
  const float* m1 = (const float*)d_in[22];
  const float* v1 = (const float*)d_in[23];
  const float* a1 = (const float*)d_in[24];
  const float* W2 = (const float*)d_in[25];
  const float* b2 = (const float*)d_in[26];
  const float* ln0g = (const float*)d_in[27];
  const float* ln0b = (const float*)d_in[28];
  const float* ln1g = (const float*)d_in[29];
  const float* ln1b = (const float*)d_in[30];

  typedef __hip_bfloat16 bf;
  const size_t MB = 1u << 20;
  const size_t KB = 1u << 10;
  char* ws = (char*)d_ws;
  // -------- attention phase (peak exactly 120 MiB) --------
  bf* PR = (bf*)(ws);                      // [8192][4096]  0..64M   P, then R in place
  bf* wot = (bf*)(ws + 64 * MB);           // [512][4096]   64..68M  (precompute only)
  bf* sc = (bf*)(ws + 64 * MB);            // [8][1024][1024] 64..80M (loop; over wot)
  bf* qbf = (bf*)(ws + 80 * MB);           // [8192][512]   80..88M
  bf* kbf = (bf*)(ws + 88 * MB);           // 88..96M
  bf* vbft = (bf*)(ws + 96 * MB);          // [8][512][1024] 96..104M
  bf* wqbf = (bf*)(ws + 104 * MB);         // [8][512][512] 104..108M
  bf* wkbf = (bf*)(ws + 108 * MB);         // 108..112M
  bf* wvbf = (bf*)(ws + 112 * MB);         // 112..116M
  bf* wqkt = (bf*)(ws + 116 * MB);         // [8][512][512] 116..120M
  bf* wvot = (bf*)(ws + 104 * MB);         // [512][4096]   over wqbf (dead after wqkt)
  float* u = (float*)(ws + 108 * MB);      // [8][8192]     over wkbf (dead after wqkt)
  float* w = (float*)(ws + 108 * MB + 256 * KB);
  float* t1 = (float*)(ws + 108 * MB + 512 * KB);   // [8][512]
  float* t2 = (float*)(ws + 108 * MB + 528 * KB);
  float* cv = (float*)(ws + 108 * MB + 544 * KB);   // [8]
  float* bvo = (float*)(ws + 108 * MB + 548 * KB);  // [512]
  // -------- post-attention (dead-region reuse) --------
  float* mha = (float*)(ws + 64 * MB);     // [8192][512] f32 over sc
  float* xbuf = (float*)(ws + 80 * MB);    // over qbf
  bf* xb = (bf*)(ws + 96 * MB);            // over vbft
  bf* h0 = (bf*)(ws);                      // [8192][2048] over PR
  bf* h1 = (bf*)(ws + 32 * MB);
  float* ff = (float*)(ws + 64 * MB);      // over mha (dead after LN0)
  bf* w0t = (bf*)(ws + 104 * MB);          // over wvot (dead after mha)
  bf* w1t = (bf*)(ws + 106 * MB);          // 106..114M
  bf* w2t = (bf*)(ws + 114 * MB);          // 114..116M

  const size_t SD = (size_t)Sd * Dd;       // 524288
  const size_t DD = (size_t)Dd * Dd;       // 262144
  const size_t SS = (size_t)Sd * Sd;       // 1048576
  const float* np = nullptr;

  // ---- conversions ----
  conv3<<<dim3(2048, 2), 256, 0, stream>>>(Q, K, K, qbf, kbf, kbf);
  conv3<<<dim3(1024, 3), 256, 0, stream>>>(WQ, WK, WV, wqbf, wkbf, wvbf);
  tconv<<<dim3(8, 16, 8), 256, 0, stream>>>(V, vbft, Dd, Sd, SD, SD);
  tconv<<<dim3(8, 64, 1), 256, 0, stream>>>(Wo, wot, Dd, Hd * Dd, 0, 0);

  // ---- folded weights ----
  bt_gemm<EPI_BF16><<<dim3(4, 4, 8), 256, 0, stream>>>(
      wkbf, Dd, 0, DD, wqbf, Dd, 0, DD, np, 0, 0,
      wqkt, Dd, 0, DD, Dd, 1.f, 3, np, np, np, np, np);
  bt_gemm<EPI_BF16><<<dim3(4, 4, 8), 256, 0, stream>>>(
      wot, Hd * Dd, 0, 512, wvbf, Dd, 0, DD, np, 0, 0,
      wvot, Hd * Dd, 0, 512, Dd, 1.f, 3, np, np, np, np, np);
  // ---- bias terms ----
  tvec<<<dim3(1024, 2), 256, 0, stream>>>(WQ, bK, WK, bQ, t1, t2);
  uw_kernel<<<Bd * Sd, 256, 0, stream>>>(Q, K, t1, t2, u, w);
  cvec<<<8, 256, 0, stream>>>(bQ, bK, cv);
  bvo_kernel<<<128, 256, 0, stream>>>(wot, bV, bo, bvo);

  // ---- P = Q @ Wqk (single GEMM M=8192 N=4096 K=512, 8-phase) ----
  big_gemm<EPI_BF16><<<dim3(16, 32), 512, 0, stream>>>(
      qbf, wqkt, np, PR, Hd * Dd, Dd, np, np, np, np, np);

  // ---- per-batch: scores -> softmax -> R (in place over P) ----
  for (int b = 0; b < Bd; ++b) {
    const size_t rowoff = (size_t)b * Sd * Hd * Dd;
    bt_gemm<EPI_SCORES><<<dim3(8, 8, 8), 256, 0, stream>>>(
        PR + rowoff, Hd * Dd, 0, 512, kbf + b * SD, Dd, 0, 0, np, 0, 0,
        sc, Sd, 0, SS, Dd, 1.f / (float)Dd, 3,
        u + b * Sd, w + b * Sd, cv, np, np);
    softmax_bf16<<<dim3(Sd, Hd), 256, 0, stream>>>(sc);
    bt_gemm<EPI_BF16><<<dim3(4, 8, 8), 256, 0, stream>>>(
        sc, Sd, 0, SS, vbft + b * SD, Sd, 0, 0, np, 0, 0,
        PR + rowoff, Hd * Dd, 0, 512, Sd, 1.f, 3, np, np, np, np, np);
  }

  // ---- mha = Rcat @ Wvo + bvo (N=512 stays on 128^2 path) ----
  bt_gemm<EPI_F32><<<dim3(4, 64, 1), 256, 0, stream>>>(
      PR, Hd * Dd, 0, 0, wvot, Hd * Dd, 0, 0, bvo, 0, 0,
      mha, Dd, 0, 0, Hd * Dd, 1.f, 0, np, np, np, np, np);
  add_ln<<<Bd * Sd, 256, 0, stream>>>(Q, mha, ln0g, ln0b, xbuf, xb);

  // ---- FF ----
  tconv<<<dim3(32, 8, 1), 256, 0, stream>>>(W0, w0t, Fd, Dd, 0, 0);
  tconv<<<dim3(32, 32, 1), 256, 0, stream>>>(W1, w1t, Fd, Fd, 0, 0);
  tconv<<<dim3(8, 32, 1), 256, 0, stream>>>(W2, w2t, Dd, Fd, 0, 0);

  big_gemm<EPI_BNPRELU><<<dim3(8, 32), 512, 0, stream>>>(
      xb, w0t, b0, h0, Fd, Dd, g0, be0, m0, v0, a0);
  big_gemm<EPI_BNPRELU><<<dim3(8, 32), 512, 0, stream>>>(
      h0, w1t, b1, h1, Fd, Fd, g1, be1, m1, v1, a1);
  bt_gemm<EPI_F32><<<dim3(4, 64, 1), 256, 0, stream>>>(
      h1, Fd, 0, 0, w2t, Fd, 0, 0, b2, 0, 0,
      ff, Dd, 0, 0, Fd, 1.f, 0, np, np, np, np, np);
  add_ln<<<Bd * Sd, 256, 0, stream>>>(xbuf, ff, ln1g, ln1b, (float*)d_out, nullptr);
}